// Round 8
// baseline (262.548 us; speedup 1.0000x reference)
//
#include <hip/hip_runtime.h>
#include <cstdint>
#include <cstddef>

// GPT-2 attention block, bf16 MFMA. B=2, S=2048, NX=1024, H=16, D=64.
// ws layout (ws is 256 MiB; fill evidence):
//   [8M,14M)  wTa  : w_attn^T as bf16     [3072][1024]
//   [14M,16M) wTp  : w_proj^T as bf16     [1024][1024]
//   [16M,40M) qkv  : bf16                 [4096][3072]
//   [40M,48M) abuf : attn out bf16        [4096][1024]
//   [48M,64M) p0   : proj split-K partial f32 [4096][1024]
//   [64M,80M) p1   : proj split-K partial f32 [4096][1024]
// (x is no longer pre-converted: gemm1 fuses f32->bf16 cvt into A staging.)

typedef __bf16 bf16;
typedef __bf16 bf16x8 __attribute__((ext_vector_type(8)));
typedef __bf16 bf16x4 __attribute__((ext_vector_type(4)));
typedef float f32x4 __attribute__((ext_vector_type(4)));
typedef float f32x16 __attribute__((ext_vector_type(16)));

#define MFMA16(a, b, c) __builtin_amdgcn_mfma_f32_16x16x32_bf16(a, b, c, 0, 0, 0)
#define MFMA32(a, b, c) __builtin_amdgcn_mfma_f32_32x32x16_bf16(a, b, c, 0, 0, 0)

typedef const __attribute__((address_space(1))) void* gas_ptr;
typedef __attribute__((address_space(3))) void* las_ptr;
__device__ __forceinline__ void async16(const void* g, void* l) {
    __builtin_amdgcn_global_load_lds((gas_ptr)g, (las_ptr)l, 16, 0, 0);
}
__device__ __forceinline__ float exp2f_fast(float x) { return __builtin_amdgcn_exp2f(x); }
__device__ __forceinline__ uint32_t pkbf(float a, float b) {
    union { bf16 x[2]; uint32_t u; } t;
    t.x[0] = (bf16)a; t.x[1] = (bf16)b;
    return t.u;
}

// ---------------- prep: transpose both weights (x-cvt now fused into gemm1) ----------------
__global__ __launch_bounds__(256) void prep_kernel(const float* __restrict__ wa, bf16* __restrict__ wTa,
                                                   const float* __restrict__ wp, bf16* __restrict__ wTp) {
    __shared__ float tile[32][33];
    const int bid = blockIdx.x, tid = threadIdx.x;
    const float* in; bf16* out; int N, t;
    if (bid < 3072) { t = bid;        in = wa; out = wTa; N = 3072; }
    else            { t = bid - 3072; in = wp; out = wTp; N = 1024; }
    const int K = 1024;
    int bx = t % (N >> 5), by = t / (N >> 5);
    int n0 = bx * 32, k0 = by * 32, tx = tid & 31, ty = tid >> 5;
#pragma unroll
    for (int i = 0; i < 32; i += 8)
        tile[ty + i][tx] = in[(size_t)(k0 + ty + i) * N + n0 + tx];
    __syncthreads();
#pragma unroll
    for (int i = 0; i < 32; i += 8)
        out[(size_t)(n0 + ty + i) * K + k0 + tx] = (bf16)tile[tx][ty + i];
}

// ---------------- bf16 GEMM 128x128, BK=32, dbuf, packed LDS, A = f32 (fused cvt) ----------------
// A staged via registers: 4x global_load_dwordx4 (f32) issued one full iteration
// ahead (drained by the barrier's vmcnt(0), same timing as the async16s), then
// cvt+pack+ds_write_b128 into the SAME packed conflict-free layout. B stays
// async16. Frag reads / MFMA / epilogue identical to the verified R5 kernel.
__global__ __launch_bounds__(256) void gemmx_kernel(const float* __restrict__ X,
                                                    const bf16* __restrict__ Bt,
                                                    const float* __restrict__ bias,
                                                    bf16* __restrict__ Cout,
                                                    int M, int N, int K) {
    __shared__ bf16 Alds[2][128 * 32];
    __shared__ bf16 Blds[2][128 * 32];
    const int tid = threadIdx.x;
    const int w = tid >> 6, l = tid & 63;
    const int lane16 = l & 15, quad = l >> 4;
    const int wr = w >> 1, wc = w & 1;

    const int nwg = gridDim.x * gridDim.y;
    const int lin = blockIdx.x + gridDim.x * blockIdx.y;
    const int q8 = nwg >> 3;
    const int swz = (lin & 7) * q8 + (lin >> 3);
    const int bx = swz % gridDim.x, by = swz / gridDim.x;
    const int row0 = by * 128, col0 = bx * 128;

    int grs[2], gks[2];
#pragma unroll
    for (int c = 0; c < 2; ++c) {
        int idx = c * 256 + tid;
        int R = idx >> 3, pos = idx & 7;
        int pos2 = pos ^ (R & 7);
        grs[c] = 2 * R + (pos2 >> 2);
        gks[c] = (pos2 & 3) * 8;
    }

    f32x4 zero4 = {0.f, 0.f, 0.f, 0.f};
    f32x4 acc[4][4];
#pragma unroll
    for (int i = 0; i < 4; ++i)
#pragma unroll
        for (int j = 0; j < 4; ++j) acc[i][j] = zero4;

    f32x4 areg[4];
    auto loadA = [&](int k0) {
#pragma unroll
        for (int c = 0; c < 2; ++c) {
            const float* src = X + (size_t)(row0 + grs[c]) * K + k0 + gks[c];
            areg[2 * c]     = *reinterpret_cast<const f32x4*>(src);
            areg[2 * c + 1] = *reinterpret_cast<const f32x4*>(src + 4);
        }
    };
    auto writeA = [&](int buf) {
#pragma unroll
        for (int c = 0; c < 2; ++c) {
            int idx = c * 256 + tid;
            bf16x8 o;
#pragma unroll
            for (int e = 0; e < 4; ++e) {
                o[e]     = (bf16)areg[2 * c][e];
                o[e + 4] = (bf16)areg[2 * c + 1][e];
            }
            *reinterpret_cast<bf16x8*>(&Alds[buf][idx * 8]) = o;
        }
    };
    auto stageB = [&](int buf, int k0) {
#pragma unroll
        for (int c = 0; c < 2; ++c) {
            int idx = c * 256 + tid;
            async16(Bt + (size_t)(col0 + grs[c]) * K + k0 + gks[c], &Blds[buf][idx * 8]);
        }
    };

    loadA(0);
    writeA(0);
    stageB(0, 0);
    loadA(32);
    const int niter = K >> 5;
    for (int it = 0; it < niter; ++it) {
        const int cur = it & 1;
        __syncthreads();
        if (it + 1 < niter) {
            writeA(cur ^ 1);                    // regs = k-step it+1 (loaded last iter)
            stageB(cur ^ 1, (it + 1) << 5);
            if (it + 2 < niter) loadA((it + 2) << 5);
        }
        bf16x8 af[4], bfr[4];
#pragma unroll
        for (int i = 0; i < 4; ++i) {
            int gra = 64 * wr + 16 * i + lane16;
            int Ra = gra >> 1;
            int pa = ((gra & 1) * 4 + quad) ^ (Ra & 7);
            af[i] = *reinterpret_cast<const bf16x8*>(&Alds[cur][Ra * 64 + pa * 8]);
            int grb = 64 * wc + 16 * i + lane16;
            int Rb = grb >> 1;
            int pb = ((grb & 1) * 4 + quad) ^ (Rb & 7);
            bfr[i] = *reinterpret_cast<const bf16x8*>(&Blds[cur][Rb * 64 + pb * 8]);
        }
#pragma unroll
        for (int i = 0; i < 4; ++i)
#pragma unroll
            for (int j = 0; j < 4; ++j) acc[i][j] = MFMA16(af[i], bfr[j], acc[i][j]);
    }

#pragma unroll
    for (int i = 0; i < 4; ++i)
#pragma unroll
        for (int j = 0; j < 4; ++j)
#pragma unroll
            for (int r = 0; r < 4; ++r) {
                int row = row0 + 64 * wr + 16 * i + quad * 4 + r;
                int col = col0 + 64 * wc + 16 * j + lane16;
                Cout[(size_t)row * N + col] = (bf16)(acc[i][j][r] + bias[col]);
            }
}

// ---------------- proj GEMM: 128x128 packed, split-K=2 -> f32 partials ----------------
// gemm2 was 253 TF at 2 blocks/CU of a 64x128 tile. Split-K=2 gives 512 blocks
// of the proven gemm1 structure (16 MFMA / 8 frag reads per iter). kz=0 adds
// bias; partials stored plain f32 (no atomics, no zero-pass); add2_kernel sums.
__global__ __launch_bounds__(256) void gemm_splitk_kernel(const bf16* __restrict__ A,
                                                          const bf16* __restrict__ Bt,
                                                          const float* __restrict__ bias,
                                                          float* __restrict__ P0,
                                                          float* __restrict__ P1,
                                                          int M, int N, int K) {
    __shared__ bf16 Alds[2][128 * 32];
    __shared__ bf16 Blds[2][128 * 32];
    const int tid = threadIdx.x;
    const int w = tid >> 6, l = tid & 63;
    const int lane16 = l & 15, quad = l >> 4;
    const int wr = w >> 1, wc = w & 1;
    const int kz = blockIdx.z;
    const int kbase = kz * (K >> 1);

    const int nwg = gridDim.x * gridDim.y;     // 256, %8==0
    const int lin = blockIdx.x + gridDim.x * blockIdx.y;
    const int q8 = nwg >> 3;
    const int swz = (lin & 7) * q8 + (lin >> 3);
    const int bx = swz % gridDim.x, by = swz / gridDim.x;
    const int row0 = by * 128, col0 = bx * 128;

    int grs[2], gks[2];
#pragma unroll
    for (int c = 0; c < 2; ++c) {
        int idx = c * 256 + tid;
        int R = idx >> 3, pos = idx & 7;
        int pos2 = pos ^ (R & 7);
        grs[c] = 2 * R + (pos2 >> 2);
        gks[c] = (pos2 & 3) * 8;
    }

    f32x4 zero4 = {0.f, 0.f, 0.f, 0.f};
    f32x4 acc[4][4];
#pragma unroll
    for (int i = 0; i < 4; ++i)
#pragma unroll
        for (int j = 0; j < 4; ++j) acc[i][j] = zero4;

    auto stage = [&](int buf, int k0) {
#pragma unroll
        for (int c = 0; c < 2; ++c) {
            int idx = c * 256 + tid;
            async16(A + (size_t)(row0 + grs[c]) * K + k0 + gks[c], &Alds[buf][idx * 8]);
            async16(Bt + (size_t)(col0 + grs[c]) * K + k0 + gks[c], &Blds[buf][idx * 8]);
        }
    };

    stage(0, kbase);
    const int niter = K >> 6;                  // 16 iters of BK=32 over K/2
    for (int it = 0; it < niter; ++it) {
        const int cur = it & 1;
        __syncthreads();
        if (it + 1 < niter) stage(cur ^ 1, kbase + ((it + 1) << 5));
        bf16x8 af[4], bfr[4];
#pragma unroll
        for (int i = 0; i < 4; ++i) {
            int gra = 64 * wr + 16 * i + lane16;
            int Ra = gra >> 1;
            int pa = ((gra & 1) * 4 + quad) ^ (Ra & 7);
            af[i] = *reinterpret_cast<const bf16x8*>(&Alds[cur][Ra * 64 + pa * 8]);
            int grb = 64 * wc + 16 * i + lane16;
            int Rb = grb >> 1;
            int pb = ((grb & 1) * 4 + quad) ^ (Rb & 7);
            bfr[i] = *reinterpret_cast<const bf16x8*>(&Blds[cur][Rb * 64 + pb * 8]);
        }
#pragma unroll
        for (int i = 0; i < 4; ++i)
#pragma unroll
            for (int j = 0; j < 4; ++j) acc[i][j] = MFMA16(af[i], bfr[j], acc[i][j]);
    }

    float* P = kz ? P1 : P0;
#pragma unroll
    for (int i = 0; i < 4; ++i)
#pragma unroll
        for (int j = 0; j < 4; ++j)
#pragma unroll
            for (int r = 0; r < 4; ++r) {
                int row = row0 + 64 * wr + 16 * i + quad * 4 + r;
                int col = col0 + 64 * wc + 16 * j + lane16;
                float v = acc[i][j][r] + (kz == 0 ? bias[col] : 0.f);
                P[(size_t)row * N + col] = v;
            }
}

__global__ __launch_bounds__(256) void add2_kernel(const f32x4* __restrict__ p0,
                                                   const f32x4* __restrict__ p1,
                                                   f32x4* __restrict__ o) {
    int i = (blockIdx.x * 256 + threadIdx.x) * 2;
    o[i]     = p0[i]     + p1[i];
    o[i + 1] = p0[i + 1] + p1[i + 1];
}

// ---------------- flash attention: 32x32 MFMA + in-reg softmax (R7), LDS = 32 KB ----------------
// R7 structure unchanged except LDS trimmed 33280 -> 32768 B: Lbuf now aliases
// the post-loop-dead Vt region (Obuf already aliases Klds). 160/32 = 5 blocks/CU
// residency (was 4) -> scheduler backfills the non-uniform block tail.
__global__ __launch_bounds__(256, 5) void attn_kernel(const bf16* __restrict__ qkv,
                                                      bf16* __restrict__ aout) {
    const int S = 2048;
    const int bh = blockIdx.x;
    const int b = bh >> 4, hd = bh & 15;
    const int rr = blockIdx.y >> 3, j = blockIdx.y & 7;
    const int qt = (rr == 0) ? (31 - j) : (rr == 1) ? (16 + j) : (rr == 2) ? (15 - j) : j;
    const int nkt = qt + 1;
    const int tid = threadIdx.x, w = tid >> 6, l = tid & 63;
    const int lane32 = l & 31, h = l >> 5;
    const int qh = w & 1, kh = w >> 1;

    __shared__ __align__(16) char smem[32768];
    bf16* Ksh = reinterpret_cast<bf16*>(smem);            // [2][64*64] swizzled
    bf16* Vsh = reinterpret_cast<bf16*>(smem + 16384);    // [2][64*64] swizzled
    float* Obuf = reinterpret_cast<float*>(smem);         // post-loop: [64 q][64 d] f32
    float* Lb = reinterpret_cast<float*>(smem + 16384);   // post-loop: [kh*2+qh][32]

    const bf16* base = qkv + (size_t)b * S * 3072;
    const float qscale = 0.125f * 1.4426950408889634f;
    const float NEGs = -10000.0f * 1.4426950408889634f;

    bf16x8 qf[4];
    {
        const bf16* qp = base + (size_t)(qt * 64 + qh * 32 + lane32) * 3072 + hd * 64;
#pragma unroll
        for (int s = 0; s < 4; ++s) {
            bf16x8 t = *reinterpret_cast<const bf16x8*>(qp + s * 16 + h * 8);
#pragma unroll
            for (int jj = 0; jj < 8; ++jj) t[jj] = (bf16)((float)t[jj] * qscale);
            qf[s] = t;
        }
    }

    f32x16 oacc[2];
#pragma unroll
    for (int dt = 0; dt < 2; ++dt)
#pragma unroll
        for (int i = 0; i < 16; ++i) oacc[dt][i] = 0.f;
    float lsum = 0.f;

    const int kr = tid >> 3, kcc = tid & 7;
    const int vp = tid & 31, vd = (tid >> 5) * 8;
    bf16x8 kreg0, kreg1, vreg0, vreg1;
    auto load_tile = [&](int kt) {
        const bf16* tb = base + (size_t)(kt * 64) * 3072;
        kreg0 = *reinterpret_cast<const bf16x8*>(tb + (size_t)kr * 3072 + 1024 + hd * 64 + kcc * 8);
        kreg1 = *reinterpret_cast<const bf16x8*>(tb + (size_t)(32 + kr) * 3072 + 1024 + hd * 64 + kcc * 8);
        vreg0 = *reinterpret_cast<const bf16x8*>(tb + (size_t)(2 * vp) * 3072 + 2048 + hd * 64 + vd);
        vreg1 = *reinterpret_cast<const bf16x8*>(tb + (size_t)(2 * vp + 1) * 3072 + 2048 + hd * 64 + vd);
    };
    auto write_KV = [&](int buf) {
        bf16* Kb = Ksh + buf * 4096;
        bf16* Vb = Vsh + buf * 4096;
        const int kchunk = kcc ^ (kr & 7);
        *reinterpret_cast<bf16x8*>(&Kb[kr * 64 + kchunk * 8]) = kreg0;
        *reinterpret_cast<bf16x8*>(&Kb[(32 + kr) * 64 + kchunk * 8]) = kreg1;
#pragma unroll
        for (int jj = 0; jj < 8; ++jj) {
            int row = vd + jj;
            union { bf16 h2v[2]; uint32_t u; } pk;
            pk.h2v[0] = vreg0[jj]; pk.h2v[1] = vreg1[jj];
            int idx = row * 64 + (((vp >> 2) ^ (row & 7)) * 8) + (vp & 3) * 2;
            *reinterpret_cast<uint32_t*>(&Vb[idx]) = pk.u;
        }
    };

    load_tile(0);
    write_KV(0);
    if (nkt > 1) load_tile(1);
    __syncthreads();

    const int krow = kh * 32 + lane32;
    for (int kt = 0; kt < nkt; ++kt) {
        const int p = kt & 1;
        if (kt + 1 < nkt) write_KV(p ^ 1);

        f32x16 st;
#pragma unroll
        for (int i = 0; i < 16; ++i) st[i] = 0.f;
        __builtin_amdgcn_s_setprio(1);
#pragma unroll
        for (int s = 0; s < 4; ++s) {
            int ch = (2 * s + h) ^ (krow & 7);
            bf16x8 kf = *reinterpret_cast<const bf16x8*>(&Ksh[p * 4096 + krow * 64 + ch * 8]);
            st = MFMA32(kf, qf[s], st);
        }
        __builtin_amdgcn_s_setprio(0);

        if (kt + 2 < nkt) load_tile(kt + 2);

        if (kt == qt) {
            const int q = qh * 32 + lane32;
#pragma unroll
            for (int reg = 0; reg < 16; ++reg) {
                int kloc = kh * 32 + 4 * h + (reg & 3) + 8 * (reg >> 2);
                if (kloc > q) st[reg] = NEGs;
            }
        }

        uint32_t wpk[4][2];
        float rs = 0.f;
#pragma unroll
        for (int g = 0; g < 4; ++g) {
            float p0 = exp2f_fast(st[4 * g + 0]);
            float p1 = exp2f_fast(st[4 * g + 1]);
            float p2 = exp2f_fast(st[4 * g + 2]);
            float p3 = exp2f_fast(st[4 * g + 3]);
            rs += (p0 + p1) + (p2 + p3);
            wpk[g][0] = pkbf(p0, p1);
            wpk[g][1] = pkbf(p2, p3);
        }
        lsum += rs;

        uint32_t opk[4][2];
#pragma unroll
        for (int g = 0; g < 4; ++g) {
            opk[g][0] = (uint32_t)__shfl_xor((int)wpk[g][0], 32, 64);
            opk[g][1] = (uint32_t)__shfl_xor((int)wpk[g][1], 32, 64);
        }

        bf16x8 pf[2];
#pragma unroll
        for (int s2 = 0; s2 < 2; ++s2) {
            union { uint32_t u[4]; bf16x8 v; } pu;
            const int g0 = 2 * s2, g1 = 2 * s2 + 1;
            pu.u[0] = h ? opk[g1][0] : wpk[g0][0];
            pu.u[1] = h ? opk[g1][1] : wpk[g0][1];
            pu.u[2] = h ? wpk[g1][0] : opk[g0][0];
            pu.u[3] = h ? wpk[g1][1] : opk[g0][1];
            pf[s2] = pu.v;
        }

        __builtin_amdgcn_s_setprio(1);
#pragma unroll
        for (int dt = 0; dt < 2; ++dt) {
            int vrow = dt * 32 + lane32;
#pragma unroll
            for (int s2 = 0; s2 < 2; ++s2) {
                int kc = (4 * kh + 2 * s2 + h) ^ (vrow & 7);
                bf16x8 vf = *reinterpret_cast<const bf16x8*>(&Vsh[p * 4096 + vrow * 64 + kc * 8]);
                oacc[dt] = MFMA32(pf[s2], vf, oacc[dt]);
            }
        }
        __builtin_amdgcn_s_setprio(0);

        __syncthreads();
    }

    lsum += __shfl_xor(lsum, 32, 64);
    if (l < 32) Lb[(kh * 2 + qh) * 32 + lane32] = lsum;

    if (kh == 1) {
#pragma unroll
        for (int dt = 0; dt < 2; ++dt)
#pragma unroll
            for (int reg = 0; reg < 16; ++reg) {
                int qrow = (reg & 3) + 8 * (reg >> 2) + 4 * h;
                Obuf[(qh * 32 + qrow) * 64 + dt * 32 + lane32] = oacc[dt][reg];
            }
    }
    __syncthreads();

    if (kh == 0) {
        float linv[16];
#pragma unroll
        for (int reg = 0; reg < 16; ++reg) {
            int qrow = (reg & 3) + 8 * (reg >> 2) + 4 * h;
            linv[reg] = 1.0f / (Lb[(0 * 2 + qh) * 32 + qrow] + Lb[(1 * 2 + qh) * 32 + qrow]);
        }
#pragma unroll
        for (int dt = 0; dt < 2; ++dt)
#pragma unroll
            for (int reg = 0; reg < 16; ++reg) {
                int qrow = (reg & 3) + 8 * (reg >> 2) + 4 * h;
                float v = (oacc[dt][reg] + Obuf[(qh * 32 + qrow) * 64 + dt * 32 + lane32]) * linv[reg];
                aout[(size_t)(b * S + qt * 64 + qh * 32 + qrow) * 1024 + hd * 64 + dt * 32 + lane32] =
                    (bf16)v;
            }
    }
}

extern "C" void kernel_launch(void* const* d_in, const int* in_sizes, int n_in,
                              void* d_out, int out_size, void* d_ws, size_t ws_size,
                              hipStream_t stream) {
    const float* x      = (const float*)d_in[0];
    const float* w_attn = (const float*)d_in[1];
    const float* b_attn = (const float*)d_in[2];
    const float* w_proj = (const float*)d_in[3];
    const float* b_proj = (const float*)d_in[4];
    float* out = (float*)d_out;
    char* ws = (char*)d_ws;

    const int Mtok = 4096, NX = 1024, N3 = 3072;
    bf16* wTa  = (bf16*)(ws + ((size_t)8 << 20));
    bf16* wTp  = (bf16*)(ws + ((size_t)14 << 20));
    bf16* qkv  = (bf16*)(ws + ((size_t)16 << 20));
    bf16* abuf = (bf16*)(ws + ((size_t)40 << 20));
    float* p0  = (float*)(ws + ((size_t)48 << 20));
    float* p1  = (float*)(ws + ((size_t)64 << 20));

    prep_kernel<<<dim3(4096), 256, 0, stream>>>(w_attn, wTa, w_proj, wTp);
    gemmx_kernel<<<dim3(N3 / 128, Mtok / 128), 256, 0, stream>>>(x, wTa, b_attn, qkv, Mtok, N3, NX);
    attn_kernel<<<dim3(32, 32), 256, 0, stream>>>(qkv, abuf);
    gemm_splitk_kernel<<<dim3(NX / 128, Mtok / 128, 2), 256, 0, stream>>>(abuf, wTp, b_proj, p0, p1, Mtok, NX, NX);
    add2_kernel<<<dim3(2048), 256, 0, stream>>>((const f32x4*)p0, (const f32x4*)p1, (f32x4*)out);
}

// Round 9
// 169.354 us; speedup vs baseline: 1.5503x; 1.5503x over previous
//
#include <hip/hip_runtime.h>
#include <cstdint>
#include <cstddef>

// GPT-2 attention block, bf16 MFMA. B=2, S=2048, NX=1024, H=16, D=64.
// ws layout (48 MiB used):
//   [0,8M)    xb   : x as bf16            [4096][1024]
//   [8M,14M)  wTa  : w_attn^T as bf16     [3072][1024]
//   [14M,16M) wTp  : w_proj^T as bf16     [1024][1024]
//   [16M,40M) qkv  : bf16                 [4096][3072]
//   [40M,48M) abuf : attn out bf16        [4096][1024]

typedef __bf16 bf16;
typedef __bf16 bf16x8 __attribute__((ext_vector_type(8)));
typedef __bf16 bf16x4 __attribute__((ext_vector_type(4)));
typedef float f32x4 __attribute__((ext_vector_type(4)));
typedef float f32x16 __attribute__((ext_vector_type(16)));

#define MFMA16(a, b, c) __builtin_amdgcn_mfma_f32_16x16x32_bf16(a, b, c, 0, 0, 0)
#define MFMA32(a, b, c) __builtin_amdgcn_mfma_f32_32x32x16_bf16(a, b, c, 0, 0, 0)

typedef const __attribute__((address_space(1))) void* gas_ptr;
typedef __attribute__((address_space(3))) void* las_ptr;
__device__ __forceinline__ void async16(const void* g, void* l) {
    __builtin_amdgcn_global_load_lds((gas_ptr)g, (las_ptr)l, 16, 0, 0);
}
__device__ __forceinline__ float exp2f_fast(float x) { return __builtin_amdgcn_exp2f(x); }
__device__ __forceinline__ uint32_t pkbf(float a, float b) {
    union { bf16 x[2]; uint32_t u; } t;
    t.x[0] = (bf16)a; t.x[1] = (bf16)b;
    return t.u;
}

// ---------------- fused prep: cvt x->bf16 + transpose both weights (R7) ----------------
__global__ __launch_bounds__(256) void prep_kernel(const float* __restrict__ x, bf16* __restrict__ xb,
                                                   const float* __restrict__ wa, bf16* __restrict__ wTa,
                                                   const float* __restrict__ wp, bf16* __restrict__ wTp) {
    __shared__ float tile[32][33];
    const int bid = blockIdx.x, tid = threadIdx.x;
    if (bid < 4096) {
        int i = (bid * 256 + tid) * 4;
        float4 v = *reinterpret_cast<const float4*>(x + i);
        bf16x4 o;
        o[0] = (bf16)v.x; o[1] = (bf16)v.y; o[2] = (bf16)v.z; o[3] = (bf16)v.w;
        *reinterpret_cast<bf16x4*>(xb + i) = o;
        return;
    }
    const float* in; bf16* out; int N, t;
    if (bid < 7168) { t = bid - 4096; in = wa; out = wTa; N = 3072; }
    else            { t = bid - 7168; in = wp; out = wTp; N = 1024; }
    const int K = 1024;
    int bx = t % (N >> 5), by = t / (N >> 5);
    int n0 = bx * 32, k0 = by * 32, tx = tid & 31, ty = tid >> 5;
#pragma unroll
    for (int i = 0; i < 32; i += 8)
        tile[ty + i][tx] = in[(size_t)(k0 + ty + i) * N + n0 + tx];
    __syncthreads();
#pragma unroll
    for (int i = 0; i < 32; i += 8)
        out[(size_t)(n0 + ty + i) * K + k0 + tx] = (bf16)tile[tx][ty + i];
}

// ---------------- bf16 GEMM 128x128, BK=32, dbuf, packed conflict-free LDS (R5/R7) ----------------
template <int OUT_BF16>
__global__ __launch_bounds__(256) void gemm_kernel(const bf16* __restrict__ A,
                                                   const bf16* __restrict__ Bt,
                                                   const float* __restrict__ bias,
                                                   void* __restrict__ Cout,
                                                   int M, int N, int K) {
    __shared__ bf16 Alds[2][128 * 32];
    __shared__ bf16 Blds[2][128 * 32];
    const int tid = threadIdx.x;
    const int w = tid >> 6, l = tid & 63;
    const int lane16 = l & 15, quad = l >> 4;
    const int wr = w >> 1, wc = w & 1;

    const int nwg = gridDim.x * gridDim.y;
    const int lin = blockIdx.x + gridDim.x * blockIdx.y;
    const int q8 = nwg >> 3;
    const int swz = (lin & 7) * q8 + (lin >> 3);
    const int bx = swz % gridDim.x, by = swz / gridDim.x;
    const int row0 = by * 128, col0 = bx * 128;

    int grs[2], gks[2];
#pragma unroll
    for (int c = 0; c < 2; ++c) {
        int idx = c * 256 + tid;
        int R = idx >> 3, pos = idx & 7;
        int pos2 = pos ^ (R & 7);
        grs[c] = 2 * R + (pos2 >> 2);
        gks[c] = (pos2 & 3) * 8;
    }

    f32x4 zero4 = {0.f, 0.f, 0.f, 0.f};
    f32x4 acc[4][4];
#pragma unroll
    for (int i = 0; i < 4; ++i)
#pragma unroll
        for (int j = 0; j < 4; ++j) acc[i][j] = zero4;

    auto stage = [&](int buf, int k0) {
#pragma unroll
        for (int c = 0; c < 2; ++c) {
            int idx = c * 256 + tid;
            async16(A + (size_t)(row0 + grs[c]) * K + k0 + gks[c], &Alds[buf][idx * 8]);
            async16(Bt + (size_t)(col0 + grs[c]) * K + k0 + gks[c], &Blds[buf][idx * 8]);
        }
    };

    stage(0, 0);
    const int niter = K >> 5;
    for (int it = 0; it < niter; ++it) {
        const int cur = it & 1;
        __syncthreads();
        if (it + 1 < niter) stage(cur ^ 1, (it + 1) << 5);
        bf16x8 af[4], bfr[4];
#pragma unroll
        for (int i = 0; i < 4; ++i) {
            int gra = 64 * wr + 16 * i + lane16;
            int Ra = gra >> 1;
            int pa = ((gra & 1) * 4 + quad) ^ (Ra & 7);
            af[i] = *reinterpret_cast<const bf16x8*>(&Alds[cur][Ra * 64 + pa * 8]);
            int grb = 64 * wc + 16 * i + lane16;
            int Rb = grb >> 1;
            int pb = ((grb & 1) * 4 + quad) ^ (Rb & 7);
            bfr[i] = *reinterpret_cast<const bf16x8*>(&Blds[cur][Rb * 64 + pb * 8]);
        }
#pragma unroll
        for (int i = 0; i < 4; ++i)
#pragma unroll
            for (int j = 0; j < 4; ++j) acc[i][j] = MFMA16(af[i], bfr[j], acc[i][j]);
    }

#pragma unroll
    for (int i = 0; i < 4; ++i)
#pragma unroll
        for (int j = 0; j < 4; ++j)
#pragma unroll
            for (int r = 0; r < 4; ++r) {
                int row = row0 + 64 * wr + 16 * i + quad * 4 + r;
                int col = col0 + 64 * wc + 16 * j + lane16;
                float v = acc[i][j][r] + bias[col];
                if (OUT_BF16)
                    reinterpret_cast<bf16*>(Cout)[(size_t)row * N + col] = (bf16)v;
                else
                    reinterpret_cast<float*>(Cout)[(size_t)row * N + col] = v;
            }
}

// ---------------- bf16 GEMM 64x128, BK=64, XOR-swizzled LDS, dbuf (R4/R7) ----------------
template <int OUT_BF16>
__global__ __launch_bounds__(256) void gemm64k_kernel(const bf16* __restrict__ A,
                                                      const bf16* __restrict__ Bt,
                                                      const float* __restrict__ bias,
                                                      void* __restrict__ Cout,
                                                      int M, int N, int K) {
    __shared__ bf16 Alds[2][64 * 64];
    __shared__ bf16 Blds[2][128 * 64];
    const int tid = threadIdx.x;
    const int w = tid >> 6, l = tid & 63;
    const int lane16 = l & 15, quad = l >> 4;
    const int wr = w >> 1, wc = w & 1;
    const int row0 = blockIdx.y * 64, col0 = blockIdx.x * 128;

    f32x4 zero4 = {0.f, 0.f, 0.f, 0.f};
    f32x4 acc[2][4];
#pragma unroll
    for (int i = 0; i < 2; ++i)
#pragma unroll
        for (int j = 0; j < 4; ++j) acc[i][j] = zero4;

    auto stage = [&](int buf, int k0) {
#pragma unroll
        for (int c = 0; c < 2; ++c) {
            int idx = c * 256 + tid;
            int r = idx >> 3, cc = idx & 7, gc = cc ^ (r & 7);
            async16(A + (size_t)(row0 + r) * K + k0 + gc * 8, &Alds[buf][idx * 8]);
        }
#pragma unroll
        for (int c = 0; c < 4; ++c) {
            int idx = c * 256 + tid;
            int r = idx >> 3, cc = idx & 7, gc = cc ^ (r & 7);
            async16(Bt + (size_t)(col0 + r) * K + k0 + gc * 8, &Blds[buf][idx * 8]);
        }
    };

    stage(0, 0);
    const int niter = K >> 6;
    for (int it = 0; it < niter; ++it) {
        const int cur = it & 1;
        __syncthreads();
        if (it + 1 < niter) stage(cur ^ 1, (it + 1) << 6);
        bf16x8 af[2][2], bfr[4][2];
#pragma unroll
        for (int i = 0; i < 2; ++i) {
            int r = 32 * wr + 16 * i + lane16;
#pragma unroll
            for (int ks = 0; ks < 2; ++ks) {
                int cc = (quad + 4 * ks) ^ (r & 7);
                af[i][ks] = *reinterpret_cast<const bf16x8*>(&Alds[cur][r * 64 + cc * 8]);
            }
        }
#pragma unroll
        for (int j = 0; j < 4; ++j) {
            int r = 64 * wc + 16 * j + lane16;
#pragma unroll
            for (int ks = 0; ks < 2; ++ks) {
                int cc = (quad + 4 * ks) ^ (r & 7);
                bfr[j][ks] = *reinterpret_cast<const bf16x8*>(&Blds[cur][r * 64 + cc * 8]);
            }
        }
#pragma unroll
        for (int ks = 0; ks < 2; ++ks)
#pragma unroll
            for (int i = 0; i < 2; ++i)
#pragma unroll
                for (int j = 0; j < 4; ++j) acc[i][j] = MFMA16(af[i][ks], bfr[j][ks], acc[i][j]);
    }

#pragma unroll
    for (int i = 0; i < 2; ++i)
#pragma unroll
        for (int j = 0; j < 4; ++j)
#pragma unroll
            for (int r = 0; r < 4; ++r) {
                int row = row0 + 32 * wr + 16 * i + quad * 4 + r;
                int col = col0 + 64 * wc + 16 * j + lane16;
                float v = acc[i][j][r] + bias[col];
                if (OUT_BF16)
                    reinterpret_cast<bf16*>(Cout)[(size_t)row * N + col] = (bf16)v;
                else
                    reinterpret_cast<float*>(Cout)[(size_t)row * N + col] = v;
            }
}

// ---------------- flash attention: 32x32 MFMA + in-reg softmax (R7), 32 KB LDS, lb(256,4) ----------------
// R8 post-mortem: __launch_bounds__(256,5) capped VGPR at 48 -> spill storm
// (WRITE_SIZE 8MB->64MB, 113us). Keep the CORRECT parts of R8 (32KB aliased
// smem, refcheck'd) with launch_bounds(256,4): register cap stays 128 (no
// spills possible; allocator used ~64-96 here), and the HW may co-schedule a
// 5th block/CU via the LDS headroom if VGPRs permit. Also: at kt==qt the
// (qh=0,kh=1) waves' quadrant is fully masked (k >= qt*64+32 > all q) --
// wave-uniform skip of that QK^T+softmax+PV frees issue slots for co-resident
// blocks.
__global__ __launch_bounds__(256, 4) void attn_kernel(const bf16* __restrict__ qkv,
                                                      bf16* __restrict__ aout) {
    const int S = 2048;
    const int bh = blockIdx.x;
    const int b = bh >> 4, hd = bh & 15;
    const int rr = blockIdx.y >> 3, j = blockIdx.y & 7;
    const int qt = (rr == 0) ? (31 - j) : (rr == 1) ? (16 + j) : (rr == 2) ? (15 - j) : j;
    const int nkt = qt + 1;
    const int tid = threadIdx.x, w = tid >> 6, l = tid & 63;
    const int lane32 = l & 31, h = l >> 5;
    const int qh = w & 1, kh = w >> 1;

    __shared__ __align__(16) char smem[32768];
    bf16* Ksh = reinterpret_cast<bf16*>(smem);            // [2][64*64] swizzled
    bf16* Vsh = reinterpret_cast<bf16*>(smem + 16384);    // [2][64*64] swizzled
    float* Obuf = reinterpret_cast<float*>(smem);         // post-loop alias: [64 q][64 d] f32
    float* Lb = reinterpret_cast<float*>(smem + 16384);   // post-loop alias: [kh*2+qh][32]

    const bf16* base = qkv + (size_t)b * S * 3072;
    const float qscale = 0.125f * 1.4426950408889634f;
    const float NEGs = -10000.0f * 1.4426950408889634f;

    bf16x8 qf[4];
    {
        const bf16* qp = base + (size_t)(qt * 64 + qh * 32 + lane32) * 3072 + hd * 64;
#pragma unroll
        for (int s = 0; s < 4; ++s) {
            bf16x8 t = *reinterpret_cast<const bf16x8*>(qp + s * 16 + h * 8);
#pragma unroll
            for (int jj = 0; jj < 8; ++jj) t[jj] = (bf16)((float)t[jj] * qscale);
            qf[s] = t;
        }
    }

    f32x16 oacc[2];
#pragma unroll
    for (int dt = 0; dt < 2; ++dt)
#pragma unroll
        for (int i = 0; i < 16; ++i) oacc[dt][i] = 0.f;
    float lsum = 0.f;

    const int kr = tid >> 3, kcc = tid & 7;
    const int vp = tid & 31, vd = (tid >> 5) * 8;
    bf16x8 kreg0, kreg1, vreg0, vreg1;
    auto load_tile = [&](int kt) {
        const bf16* tb = base + (size_t)(kt * 64) * 3072;
        kreg0 = *reinterpret_cast<const bf16x8*>(tb + (size_t)kr * 3072 + 1024 + hd * 64 + kcc * 8);
        kreg1 = *reinterpret_cast<const bf16x8*>(tb + (size_t)(32 + kr) * 3072 + 1024 + hd * 64 + kcc * 8);
        vreg0 = *reinterpret_cast<const bf16x8*>(tb + (size_t)(2 * vp) * 3072 + 2048 + hd * 64 + vd);
        vreg1 = *reinterpret_cast<const bf16x8*>(tb + (size_t)(2 * vp + 1) * 3072 + 2048 + hd * 64 + vd);
    };
    auto write_KV = [&](int buf) {
        bf16* Kb = Ksh + buf * 4096;
        bf16* Vb = Vsh + buf * 4096;
        const int kchunk = kcc ^ (kr & 7);
        *reinterpret_cast<bf16x8*>(&Kb[kr * 64 + kchunk * 8]) = kreg0;
        *reinterpret_cast<bf16x8*>(&Kb[(32 + kr) * 64 + kchunk * 8]) = kreg1;
#pragma unroll
        for (int jj = 0; jj < 8; ++jj) {
            int row = vd + jj;
            union { bf16 h2v[2]; uint32_t u; } pk;
            pk.h2v[0] = vreg0[jj]; pk.h2v[1] = vreg1[jj];
            int idx = row * 64 + (((vp >> 2) ^ (row & 7)) * 8) + (vp & 3) * 2;
            *reinterpret_cast<uint32_t*>(&Vb[idx]) = pk.u;
        }
    };

    load_tile(0);
    write_KV(0);
    if (nkt > 1) load_tile(1);
    __syncthreads();

    const int krow = kh * 32 + lane32;
    for (int kt = 0; kt < nkt; ++kt) {
        const int p = kt & 1;
        if (kt + 1 < nkt) write_KV(p ^ 1);

        // fully-masked quadrant (k >= qt*64+32 > all q of qh=0): skip compute
        if (kt == qt && kh == 1 && qh == 0) { __syncthreads(); continue; }

        f32x16 st;
#pragma unroll
        for (int i = 0; i < 16; ++i) st[i] = 0.f;
        __builtin_amdgcn_s_setprio(1);
#pragma unroll
        for (int s = 0; s < 4; ++s) {
            int ch = (2 * s + h) ^ (krow & 7);
            bf16x8 kf = *reinterpret_cast<const bf16x8*>(&Ksh[p * 4096 + krow * 64 + ch * 8]);
            st = MFMA32(kf, qf[s], st);
        }
        __builtin_amdgcn_s_setprio(0);

        if (kt + 2 < nkt) load_tile(kt + 2);

        if (kt == qt) {
            const int q = qh * 32 + lane32;
#pragma unroll
            for (int reg = 0; reg < 16; ++reg) {
                int kloc = kh * 32 + 4 * h + (reg & 3) + 8 * (reg >> 2);
                if (kloc > q) st[reg] = NEGs;
            }
        }

        uint32_t wpk[4][2];
        float rs = 0.f;
#pragma unroll
        for (int g = 0; g < 4; ++g) {
            float p0 = exp2f_fast(st[4 * g + 0]);
            float p1 = exp2f_fast(st[4 * g + 1]);
            float p2 = exp2f_fast(st[4 * g + 2]);
            float p3 = exp2f_fast(st[4 * g + 3]);
            rs += (p0 + p1) + (p2 + p3);
            wpk[g][0] = pkbf(p0, p1);
            wpk[g][1] = pkbf(p2, p3);
        }
        lsum += rs;

        uint32_t opk[4][2];
#pragma unroll
        for (int g = 0; g < 4; ++g) {
            opk[g][0] = (uint32_t)__shfl_xor((int)wpk[g][0], 32, 64);
            opk[g][1] = (uint32_t)__shfl_xor((int)wpk[g][1], 32, 64);
        }

        bf16x8 pf[2];
#pragma unroll
        for (int s2 = 0; s2 < 2; ++s2) {
            union { uint32_t u[4]; bf16x8 v; } pu;
            const int g0 = 2 * s2, g1 = 2 * s2 + 1;
            pu.u[0] = h ? opk[g1][0] : wpk[g0][0];
            pu.u[1] = h ? opk[g1][1] : wpk[g0][1];
            pu.u[2] = h ? wpk[g1][0] : opk[g0][0];
            pu.u[3] = h ? wpk[g1][1] : opk[g0][1];
            pf[s2] = pu.v;
        }

        __builtin_amdgcn_s_setprio(1);
#pragma unroll
        for (int dt = 0; dt < 2; ++dt) {
            int vrow = dt * 32 + lane32;
#pragma unroll
            for (int s2 = 0; s2 < 2; ++s2) {
                int kc = (4 * kh + 2 * s2 + h) ^ (vrow & 7);
                bf16x8 vf = *reinterpret_cast<const bf16x8*>(&Vsh[p * 4096 + vrow * 64 + kc * 8]);
                oacc[dt] = MFMA32(pf[s2], vf, oacc[dt]);
            }
        }
        __builtin_amdgcn_s_setprio(0);

        __syncthreads();
    }

    lsum += __shfl_xor(lsum, 32, 64);
    if (l < 32) Lb[(kh * 2 + qh) * 32 + lane32] = lsum;

    if (kh == 1) {
#pragma unroll
        for (int dt = 0; dt < 2; ++dt)
#pragma unroll
            for (int reg = 0; reg < 16; ++reg) {
                int qrow = (reg & 3) + 8 * (reg >> 2) + 4 * h;
                Obuf[(qh * 32 + qrow) * 64 + dt * 32 + lane32] = oacc[dt][reg];
            }
    }
    __syncthreads();

    if (kh == 0) {
        float linv[16];
#pragma unroll
        for (int reg = 0; reg < 16; ++reg) {
            int qrow = (reg & 3) + 8 * (reg >> 2) + 4 * h;
            linv[reg] = 1.0f / (Lb[(0 * 2 + qh) * 32 + qrow] + Lb[(1 * 2 + qh) * 32 + qrow]);
        }
#pragma unroll
        for (int dt = 0; dt < 2; ++dt)
#pragma unroll
            for (int reg = 0; reg < 16; ++reg) {
                int qrow = (reg & 3) + 8 * (reg >> 2) + 4 * h;
                float v = (oacc[dt][reg] + Obuf[(qh * 32 + qrow) * 64 + dt * 32 + lane32]) * linv[reg];
                aout[(size_t)(b * S + qt * 64 + qh * 32 + qrow) * 1024 + hd * 64 + dt * 32 + lane32] =
                    (bf16)v;
            }
    }
}

extern "C" void kernel_launch(void* const* d_in, const int* in_sizes, int n_in,
                              void* d_out, int out_size, void* d_ws, size_t ws_size,
                              hipStream_t stream) {
    const float* x      = (const float*)d_in[0];
    const float* w_attn = (const float*)d_in[1];
    const float* b_attn = (const float*)d_in[2];
    const float* w_proj = (const float*)d_in[3];
    const float* b_proj = (const float*)d_in[4];
    float* out = (float*)d_out;
    char* ws = (char*)d_ws;

    const int Mtok = 4096, NX = 1024, N3 = 3072;
    bf16* xb   = (bf16*)(ws);
    bf16* wTa  = (bf16*)(ws + ((size_t)8 << 20));
    bf16* wTp  = (bf16*)(ws + ((size_t)14 << 20));
    bf16* qkv  = (bf16*)(ws + ((size_t)16 << 20));
    bf16* abuf = (bf16*)(ws + ((size_t)40 << 20));

    prep_kernel<<<dim3(8192), 256, 0, stream>>>(x, xb, w_attn, wTa, w_proj, wTp);
    gemm_kernel<1><<<dim3(N3 / 128, Mtok / 128), 256, 0, stream>>>(xb, wTa, b_attn, qkv, Mtok, N3, NX);
    attn_kernel<<<dim3(32, 32), 256, 0, stream>>>(qkv, abuf);
    gemm64k_kernel<0><<<dim3(NX / 128, Mtok / 64), 256, 0, stream>>>(abuf, wTp, b_proj, out, Mtok, NX, NX);
}